// Round 6
// baseline (276.189 us; speedup 1.0000x reference)
//
#include <hip/hip_runtime.h>

#define NBLOCKS 4096
#define NTHREADS 256
#define GROUPS 8
// 4096 blocks * 256 threads = 2^20 threads; each handles 8 float4 groups
// -> 2^23 float4 = 2^25 elements exactly.

typedef float fvec4 __attribute__((ext_vector_type(4)));
typedef int   ivec4 __attribute__((ext_vector_type(4)));

__device__ __forceinline__ fvec4 ntloadf(const fvec4* p) {
    return __builtin_nontemporal_load(p);
}
__device__ __forceinline__ ivec4 ntloadi(const ivec4* p) {
    return __builtin_nontemporal_load(p);
}

__global__ __launch_bounds__(NTHREADS) void wmse_kernel(
    const fvec4* __restrict__ pred4,
    const ivec4* __restrict__ lab4,
    const float* __restrict__ weights,
    float* __restrict__ out,
    int n4, double inv_n)
{
    __shared__ float w[16];
    if (threadIdx.x < 10) w[threadIdx.x] = weights[threadIdx.x];
    __syncthreads();

    const int stride = NBLOCKS * NTHREADS;       // 2^20 float4 groups
    const int t = blockIdx.x * NTHREADS + threadIdx.x;

    double acc = 0.0;

    if (n4 == stride * GROUPS) {
        // ---- flat fast path: 16 fully independent nontemporal loads ----
        fvec4 p[GROUPS];
        ivec4 l[GROUPS];
        #pragma unroll
        for (int k = 0; k < GROUPS; ++k) {
            p[k] = ntloadf(pred4 + t + k * stride);
            l[k] = ntloadi(lab4 + t + k * stride);
        }
        #pragma unroll
        for (int k = 0; k < GROUPS; k += 2) {
            float d0 = p[k].x - (float)l[k].x;
            float d1 = p[k].y - (float)l[k].y;
            float d2 = p[k].z - (float)l[k].z;
            float d3 = p[k].w - (float)l[k].w;
            float sA = w[l[k].x]*d0*d0 + w[l[k].y]*d1*d1
                     + w[l[k].z]*d2*d2 + w[l[k].w]*d3*d3;
            float e0 = p[k+1].x - (float)l[k+1].x;
            float e1 = p[k+1].y - (float)l[k+1].y;
            float e2 = p[k+1].z - (float)l[k+1].z;
            float e3 = p[k+1].w - (float)l[k+1].w;
            float sB = w[l[k+1].x]*e0*e0 + w[l[k+1].y]*e1*e1
                     + w[l[k+1].z]*e2*e2 + w[l[k+1].w]*e3*e3;
            acc += (double)(sA + sB);
        }
    } else {
        // generic fallback (not taken for N = 2^25)
        for (int i = t; i < n4; i += stride) {
            fvec4 p = pred4[i];
            ivec4 l = lab4[i];
            float d0 = p.x - (float)l.x, d1 = p.y - (float)l.y;
            float d2 = p.z - (float)l.z, d3 = p.w - (float)l.w;
            acc += (double)(w[l.x]*d0*d0 + w[l.y]*d1*d1
                          + w[l.z]*d2*d2 + w[l.w]*d3*d3);
        }
    }

    // 64-lane wave shuffle reduction (f64)
    for (int off = 32; off > 0; off >>= 1)
        acc += __shfl_down(acc, off, 64);

    __shared__ double wave_sums[NTHREADS / 64];
    int lane = threadIdx.x & 63;
    int wid  = threadIdx.x >> 6;
    if (lane == 0) wave_sums[wid] = acc;
    __syncthreads();

    if (threadIdx.x == 0) {
        double tsum = 0.0;
        #pragma unroll
        for (int k = 0; k < NTHREADS / 64; ++k) tsum += wave_sums[k];
        atomicAdd(out, (float)(tsum * inv_n));   // out zeroed by memset node
    }
}

extern "C" void kernel_launch(void* const* d_in, const int* in_sizes, int n_in,
                              void* d_out, int out_size, void* d_ws, size_t ws_size,
                              hipStream_t stream) {
    const float* pred    = (const float*)d_in[0];
    const int*   labels  = (const int*)d_in[1];
    const float* weights = (const float*)d_in[2];
    float* out = (float*)d_out;

    int n  = in_sizes[0];          // 33,554,432 = 2^25
    int n4 = n >> 2;

    // d_out re-poisoned to 0xAA before every timed launch — zero it (4 B, cheap)
    hipMemsetAsync(out, 0, out_size * sizeof(float), stream);

    wmse_kernel<<<NBLOCKS, NTHREADS, 0, stream>>>(
        (const fvec4*)pred, (const ivec4*)labels, weights, out,
        n4, 1.0 / (double)n);
}